// Round 11
// baseline (371.846 us; speedup 1.0000x reference)
//
#include <hip/hip_runtime.h>
#include <stdint.h>

// Problem dims
#define TDIM 4096
#define HDIM 2048   // N and K of the GEMM

// GEMM tile
#define BM 128
#define BN 128
#define BK 64
#define NKT (HDIM / BK)   // 32
// LDS stage = A region (144 rows = 16 warmup + 128 main; 18 groups of 8 rows,
// 1KB/group) + B region (128 rows = 16 groups), 128B/row (BK=64 bf16).
#define ABYTES 18432
#define STAGE  34816      // ABYTES + 16384
#define NSTAGE 3          // triple buffer -> prefetch depth 2, 1 barrier/iter
#define SSTR   132        // S-tile row stride in elements (breaks bank conflicts)

typedef short short8 __attribute__((ext_vector_type(8)));
typedef float f32x4 __attribute__((ext_vector_type(4)));

__device__ __forceinline__ uint16_t f2bf(float f) {
  uint32_t u = __builtin_bit_cast(uint32_t, f);
  u += 0x7fffu + ((u >> 16) & 1u);          // round-to-nearest-even
  return (uint16_t)(u >> 16);
}
__device__ __forceinline__ float bf2f(uint32_t h) {   // low 16 bits used
  uint32_t u = h << 16;
  return __builtin_bit_cast(float, u);
}

__device__ __forceinline__ void async_copy16(const void* gsrc, void* ldst) {
  __builtin_amdgcn_global_load_lds(
      (const __attribute__((address_space(1))) uint32_t*)gsrc,
      (__attribute__((address_space(3))) uint32_t*)ldst,
      16, 0, 0);
}

// ------------- prep: cvt x (fp32->bf16) + transpose/cvt B -> Bt -------------
__global__ void prep(const float* __restrict__ x, const float* __restrict__ B,
                     uint16_t* __restrict__ xb, uint16_t* __restrict__ Bt) {
  __shared__ uint16_t tile[64][68];
  const int t = threadIdx.x;
  if (blockIdx.x < 4096) {
    size_t i = ((size_t)blockIdx.x * 256 + t) * 8;
    float4 v0 = *(const float4*)(x + i);
    float4 v1 = *(const float4*)(x + i + 4);
    union { uint16_t h[8]; uint4 v; } o;
    o.h[0] = f2bf(v0.x); o.h[1] = f2bf(v0.y); o.h[2] = f2bf(v0.z); o.h[3] = f2bf(v0.w);
    o.h[4] = f2bf(v1.x); o.h[5] = f2bf(v1.y); o.h[6] = f2bf(v1.z); o.h[7] = f2bf(v1.w);
    *(uint4*)(xb + i) = o.v;
  } else {
    const int bid = blockIdx.x - 4096;
    const int n0 = (bid & 31) * 64;
    const int k0 = (bid >> 5) * 64;
    {
      const int r  = t >> 4;
      const int c4 = (t & 15) * 4;
#pragma unroll
      for (int i = 0; i < 4; ++i) {
        int rr = r + i * 16;
        float4 v = *(const float4*)&B[(size_t)(k0 + rr) * HDIM + n0 + c4];
        union { uint16_t h[4]; uint2 u; } o;
        o.h[0] = f2bf(v.x); o.h[1] = f2bf(v.y); o.h[2] = f2bf(v.z); o.h[3] = f2bf(v.w);
        *(uint2*)&tile[rr][c4] = o.u;
      }
    }
    __syncthreads();
    {
      const int nr = t >> 2;
      const int kc = (t & 3) * 4;
#pragma unroll
      for (int i = 0; i < 4; ++i) {
        int kk = kc + i * 16;
        union { uint16_t h[4]; uint2 u; } o;
        o.h[0] = tile[kk][nr];     o.h[1] = tile[kk + 1][nr];
        o.h[2] = tile[kk + 2][nr]; o.h[3] = tile[kk + 3][nr];
        *(uint2*)&Bt[(size_t)(n0 + nr) * HDIM + k0 + kk] = o.u;
      }
    }
  }
}

// --------- fused GEMM + causal exp-decay recurrence (scan) ---------
// Split-K: 8 waves = 2 k-groups x 4 waves of 64x64 (4x4 acc). Each wave
// reads frags only for its K32 half -> per-CU-iter LDS traffic 107 KB vs
// R6's 278 KB. Triple-buffered stages, prefetch depth 2, ONE barrier/iter.
// launch_bounds(512,2): 256-reg cap, no acc spill (R8's failure). 1 block/CU.
// Cross-k reduction through LDS once at the end, then in-LDS S-tile scan.
__global__ __launch_bounds__(512, 2) void gemm_scan(
    const uint16_t* __restrict__ A, const uint16_t* __restrict__ Bt,
    const float* __restrict__ a, float* __restrict__ out) {
  __shared__ __align__(16) char lds[NSTAGE * STAGE];   // 104448 B

  const int tid  = threadIdx.x;
  const int lane = tid & 63;
  const int wave = tid >> 6;            // 0..7
  const int kg   = wave >> 2;           // k-group: 0 -> K32 half 0, 1 -> half 1
  const int wq   = wave & 3;            // quadrant within k-group
  const int wm = (wq >> 1) * 64;        // wave row offset {0,64}
  const int wn = (wq & 1) * 64;         // wave col offset {0,64}
  const int m0 = blockIdx.y * BM;
  const int n0 = blockIdx.x * BN;

  f32x4 acc[4][4] = {};                 // partial over this wave's k-half
  f32x4 accw[2] = {};                   // warmup rows: 2 col-tiles per wave

  // staging: one instr = 8 rows x 128B (1KB); lane l: row lr=l>>3, slot l&7,
  // fetches global chunk (l&7)^lr -> LDS slot c of row r holds chunk c^(r&7)
  const int lr = lane >> 3;             // 0..7
  const int gc = (lane & 7) ^ lr;       // swizzled 16B chunk to fetch

  const int fr = lane & 15;
  const int fq = lane >> 4;             // 0..3
  const int iw0 = (wq >> 1) * 2;        // warmup col-tile base: 0 or 2

  // A: 18 groups of 8 rows (t in [m0-16, m0+128)): g = wave, wave+8
  // (+16/+17 on waves 0,1). B: 16 groups: g = wave, wave+8.
  // -> 5 instr on waves 0,1; 4 on waves 2..7.
  auto issue_tile = [&](int kt2) {
    size_t koff = (size_t)kt2 * (BK * 2);
    char* dst = lds + (kt2 % NSTAGE) * STAGE;
    int g = wave;
    int row = m0 - 16 + g * 8 + lr;
    if (row < 0) row = 0;               // m0==0: garbage rows, never used
    async_copy16((const char*)A + ((size_t)row * HDIM + gc * 8) * 2 + koff,
                 dst + g * 1024);
    g = wave + 8;
    row = m0 - 16 + g * 8 + lr;         // >= m0+48: always valid
    async_copy16((const char*)A + ((size_t)row * HDIM + gc * 8) * 2 + koff,
                 dst + g * 1024);
    if (wave < 2) {
      g = 16 + wave;
      row = m0 - 16 + g * 8 + lr;       // m0+112..127: valid
      async_copy16((const char*)A + ((size_t)row * HDIM + gc * 8) * 2 + koff,
                   dst + g * 1024);
    }
#pragma unroll
    for (int i = 0; i < 2; ++i) {
      int gb = wave + i * 8;
      int rowb = n0 + gb * 8 + lr;
      async_copy16((const char*)Bt + ((size_t)rowb * HDIM + gc * 8) * 2 + koff,
                   dst + ABYTES + gb * 1024);
    }
  };

  issue_tile(0);
  issue_tile(1);

  for (int kt = 0; kt < NKT; ++kt) {
    // retire DMA(kt); DMA(kt+1) (4 or 5 instrs) stays in flight
    if (kt + 1 < NKT) {
      if (wave < 2) asm volatile("s_waitcnt vmcnt(5)" ::: "memory");
      else          asm volatile("s_waitcnt vmcnt(4)" ::: "memory");
    } else {
      asm volatile("s_waitcnt vmcnt(0)" ::: "memory");
    }
    asm volatile("s_barrier" ::: "memory");

    const char* base = lds + (kt % NSTAGE) * STAGE;
    // this wave's K32 half: demand chunk q = kg*4+fq; slot = q ^ (row&7)
    const int coff = ((kg * 4 + fq) ^ (fr & 7)) * 16;
    short8 af[4], bfr[4], aw;
#pragma unroll
    for (int im = 0; im < 4; ++im) {
      int row = 16 + wm + im * 16 + fr;               // row&7 == fr&7
      af[im] = *(const short8*)(base + row * 128 + coff);
    }
#pragma unroll
    for (int in = 0; in < 4; ++in) {
      int row = wn + in * 16 + fr;
      bfr[in] = *(const short8*)(base + ABYTES + row * 128 + coff);
    }
    aw = *(const short8*)(base + fr * 128 + coff);    // warmup rows 0..15
#pragma unroll
    for (int im = 0; im < 4; ++im)
#pragma unroll
      for (int in = 0; in < 4; ++in)
        acc[im][in] = __builtin_amdgcn_mfma_f32_16x16x32_bf16(
            af[im], bfr[in], acc[im][in], 0, 0, 0);
#pragma unroll
    for (int iw = 0; iw < 2; ++iw)
      accw[iw] = __builtin_amdgcn_mfma_f32_16x16x32_bf16(
          aw, bfr[iw0 + iw], accw[iw], 0, 0, 0);

    if (kt + 2 < NKT) issue_tile(kt + 2);   // into stage (kt+2)%3: free by
                                            // the barrier at top of this iter
  }

  // ---- cross-k reduction through LDS (one-time) ----
  __syncthreads();                      // all stage reads done; safe to reuse
  float* X = (float*)lds;               // acc: 64 KB; accw at +16384 floats
  if (kg == 1) {
#pragma unroll
    for (int im = 0; im < 4; ++im)
#pragma unroll
      for (int in = 0; in < 4; ++in)
        *(f32x4*)(X + wq * 4096 + (im * 4 + in) * 256 + lane * 4) = acc[im][in];
#pragma unroll
    for (int iw = 0; iw < 2; ++iw)
      *(f32x4*)(X + 16384 + wq * 512 + iw * 256 + lane * 4) = accw[iw];
  }
  __syncthreads();
  if (kg == 0) {
#pragma unroll
    for (int im = 0; im < 4; ++im)
#pragma unroll
      for (int in = 0; in < 4; ++in)
        acc[im][in] += *(f32x4*)(X + wq * 4096 + (im * 4 + in) * 256 + lane * 4);
#pragma unroll
    for (int iw = 0; iw < 2; ++iw)
      accw[iw] += *(f32x4*)(X + 16384 + wq * 512 + iw * 256 + lane * 4);
  }
  __syncthreads();

  // ---- S-tile (144 x 128, bf16, stride 132) into LDS ----
  uint16_t* Sl = (uint16_t*)lds;
  if (kg == 0) {
#pragma unroll
    for (int im = 0; im < 4; ++im)
#pragma unroll
      for (int in = 0; in < 4; ++in)
#pragma unroll
        for (int r = 0; r < 4; ++r)
          Sl[(16 + wm + im * 16 + fq * 4 + r) * SSTR + wn + in * 16 + fr] =
              f2bf(acc[im][in][r]);
#pragma unroll
    for (int iw = 0; iw < 2; ++iw)
#pragma unroll
      for (int r = 0; r < 4; ++r)
        Sl[(fq * 4 + r) * SSTR + wn + (iw0 + iw) * 16 + fr] = f2bf(accw[iw][r]);
  }
  __syncthreads();

  // ---- scan: 4 threads per column, 32 t-steps each, 16-step warmup ----
  const int col   = tid & 127;
  const int chunk = tid >> 7;           // 0..3
  const float av  = a[n0 + col];
  float h = 0.f;
  if (!(m0 == 0 && chunk == 0)) {
#pragma unroll
    for (int i = 0; i < 16; ++i)
      h = av * h + bf2f(Sl[(chunk * 32 + i) * SSTR + col]);
  }
  float* op = out + (size_t)(m0 + chunk * 32) * HDIM + n0 + col;
#pragma unroll
  for (int i = 0; i < 32; ++i) {
    h = av * h + bf2f(Sl[(chunk * 32 + 16 + i) * SSTR + col]);
    op[(size_t)i * HDIM] = h;
  }
}

extern "C" void kernel_launch(void* const* d_in, const int* in_sizes, int n_in,
                              void* d_out, int out_size, void* d_ws, size_t ws_size,
                              hipStream_t stream) {
  const float* x = (const float*)d_in[0];   // (T, H)
  const float* a = (const float*)d_in[1];   // (H,)
  const float* B = (const float*)d_in[2];   // (H, H)
  float* out = (float*)d_out;               // (1, T, H) fp32

  uint16_t* xb  = (uint16_t*)d_ws;                                        // 16 MB
  uint16_t* Btb = (uint16_t*)((char*)d_ws + (size_t)16 * 1024 * 1024);    //  8 MB

  // x -> bf16  and  B -> Bt bf16 (fused)
  prep<<<4096 + 1024, 256, 0, stream>>>(x, B, xb, Btb);
  // fused GEMM + recurrence: 512 blocks x 512 threads, split-K + 3-stage
  gemm_scan<<<dim3(HDIM / BN, TDIM / BM), 512, 0, stream>>>(xb, Btb, a, out);
}

// Round 12
// 141.190 us; speedup vs baseline: 2.6337x; 2.6337x over previous
//
#include <hip/hip_runtime.h>
#include <stdint.h>

// Problem dims
#define TDIM 4096
#define HDIM 2048   // N and K of the GEMM

// GEMM tile
#define BM 128
#define BN 128
#define BK 64
#define NKT (HDIM / BK)   // 32
// LDS stage = A region (144 rows = 16 warmup + 128 main; 18 groups of 8 rows,
// 1KB/group) + B region (128 rows = 16 groups), 128B/row (BK=64 bf16).
#define ABYTES 18432
#define PERBUF 34816      // ABYTES + 16384
// total LDS: max(2*PERBUF=69632, reduction 73728, S-tile 38016) = 73728
#define LDSSZ  73728
#define SSTR   132        // S-tile row stride in elements (breaks bank conflicts)

typedef short short8 __attribute__((ext_vector_type(8)));
typedef float f32x4 __attribute__((ext_vector_type(4)));

__device__ __forceinline__ uint16_t f2bf(float f) {
  uint32_t u = __builtin_bit_cast(uint32_t, f);
  u += 0x7fffu + ((u >> 16) & 1u);          // round-to-nearest-even
  return (uint16_t)(u >> 16);
}
__device__ __forceinline__ float bf2f(uint32_t h) {   // low 16 bits used
  uint32_t u = h << 16;
  return __builtin_bit_cast(float, u);
}

__device__ __forceinline__ void async_copy16(const void* gsrc, void* ldst) {
  __builtin_amdgcn_global_load_lds(
      (const __attribute__((address_space(1))) uint32_t*)gsrc,
      (__attribute__((address_space(3))) uint32_t*)ldst,
      16, 0, 0);
}

// ------------- prep: cvt x (fp32->bf16) + transpose/cvt B -> Bt -------------
__global__ void prep(const float* __restrict__ x, const float* __restrict__ B,
                     uint16_t* __restrict__ xb, uint16_t* __restrict__ Bt) {
  __shared__ uint16_t tile[64][68];
  const int t = threadIdx.x;
  if (blockIdx.x < 4096) {
    size_t i = ((size_t)blockIdx.x * 256 + t) * 8;
    float4 v0 = *(const float4*)(x + i);
    float4 v1 = *(const float4*)(x + i + 4);
    union { uint16_t h[8]; uint4 v; } o;
    o.h[0] = f2bf(v0.x); o.h[1] = f2bf(v0.y); o.h[2] = f2bf(v0.z); o.h[3] = f2bf(v0.w);
    o.h[4] = f2bf(v1.x); o.h[5] = f2bf(v1.y); o.h[6] = f2bf(v1.z); o.h[7] = f2bf(v1.w);
    *(uint4*)(xb + i) = o.v;
  } else {
    const int bid = blockIdx.x - 4096;
    const int n0 = (bid & 31) * 64;
    const int k0 = (bid >> 5) * 64;
    {
      const int r  = t >> 4;
      const int c4 = (t & 15) * 4;
#pragma unroll
      for (int i = 0; i < 4; ++i) {
        int rr = r + i * 16;
        float4 v = *(const float4*)&B[(size_t)(k0 + rr) * HDIM + n0 + c4];
        union { uint16_t h[4]; uint2 u; } o;
        o.h[0] = f2bf(v.x); o.h[1] = f2bf(v.y); o.h[2] = f2bf(v.z); o.h[3] = f2bf(v.w);
        *(uint2*)&tile[rr][c4] = o.u;
      }
    }
    __syncthreads();
    {
      const int nr = t >> 2;
      const int kc = (t & 3) * 4;
#pragma unroll
      for (int i = 0; i < 4; ++i) {
        int kk = kc + i * 16;
        union { uint16_t h[4]; uint2 u; } o;
        o.h[0] = tile[kk][nr];     o.h[1] = tile[kk + 1][nr];
        o.h[2] = tile[kk + 2][nr]; o.h[3] = tile[kk + 3][nr];
        *(uint2*)&Bt[(size_t)(n0 + nr) * HDIM + k0 + kk] = o.u;
      }
    }
  }
}

// --------- fused GEMM + causal exp-decay recurrence (scan) ---------
// Split-K: 8 waves = 2 k-groups x 4 waves of 64x64 (4x4 acc). Each wave
// reads frags only for its own K32 half of the BK=64 tile -> per-CU-iter
// LDS traffic 204 KB vs R6's 278 KB, at R6's occupancy (2 blocks/CU, two
// barrier domains). ALL register-array indices are compile-time constants
// (R8/R11 died on dynamically-indexed bfr[] -> scratch/VALU storm).
// Warmup rows (t in [m0-16,m0)) computed by the two wm==0 waves per k-group
// over their static bfr[0..3]. One-time cross-k reduction through LDS, then
// in-LDS S-tile scan (|a| <= 2^-5 -> 16-step truncation ~1e-24).
__global__ __launch_bounds__(512, 4) void gemm_scan(
    const uint16_t* __restrict__ A, const uint16_t* __restrict__ Bt,
    const float* __restrict__ a, float* __restrict__ out) {
  __shared__ __align__(16) char lds[LDSSZ];

  const int tid  = threadIdx.x;
  const int lane = tid & 63;
  const int wave = tid >> 6;            // 0..7
  const int kg   = wave >> 2;           // k-group: K32 half 0 or 1
  const int wq   = wave & 3;            // quadrant within k-group
  const int wm = (wq >> 1) * 64;        // wave row offset {0,64}
  const int wn = (wq & 1) * 64;         // wave col offset {0,64}
  const int m0 = blockIdx.y * BM;
  const int n0 = blockIdx.x * BN;

  f32x4 acc[4][4] = {};                 // partial over this wave's k-half
  f32x4 accw[4] = {};                   // warmup: only used when wm==0

  // staging: one instr = 8 rows x 128B (1KB); lane l: row lr=l>>3, slot l&7,
  // fetches global chunk (l&7)^lr -> LDS slot c of row r holds chunk c^(r&7)
  const int lr = lane >> 3;             // 0..7
  const int gc = (lane & 7) ^ lr;       // swizzled 16B chunk to fetch

  const int fr = lane & 15;
  const int fq = lane >> 4;             // 0..3

  // A: 18 groups of 8 rows (t in [m0-16, m0+128)): g = wave, wave+8
  // (+16/+17 on waves 0,1). B: 16 groups: g = wave, wave+8.
  // -> 5 instr on waves 0,1; 4 on waves 2..7.
  auto issue_tile = [&](int kt2) {
    size_t koff = (size_t)kt2 * (BK * 2);
    char* dst = lds + (kt2 & 1) * PERBUF;
    int g = wave;
    int row = m0 - 16 + g * 8 + lr;
    if (row < 0) row = 0;               // m0==0: garbage rows, never used
    async_copy16((const char*)A + ((size_t)row * HDIM + gc * 8) * 2 + koff,
                 dst + g * 1024);
    g = wave + 8;
    row = m0 - 16 + g * 8 + lr;         // >= m0+48: always valid
    async_copy16((const char*)A + ((size_t)row * HDIM + gc * 8) * 2 + koff,
                 dst + g * 1024);
    if (wave < 2) {
      g = 16 + wave;
      row = m0 - 16 + g * 8 + lr;       // m0+112..127: valid
      async_copy16((const char*)A + ((size_t)row * HDIM + gc * 8) * 2 + koff,
                   dst + g * 1024);
    }
#pragma unroll
    for (int i = 0; i < 2; ++i) {
      int gb = wave + i * 8;
      int rowb = n0 + gb * 8 + lr;
      async_copy16((const char*)Bt + ((size_t)rowb * HDIM + gc * 8) * 2 + koff,
                   dst + ABYTES + gb * 1024);
    }
  };

  issue_tile(0);
  for (int kt = 0; kt < NKT; ++kt) {
    if (kt + 1 < NKT) {
      issue_tile(kt + 1);
      // retire tile kt's DMA; tile kt+1's (5 or 4) stay in flight
      if (wave < 2) asm volatile("s_waitcnt vmcnt(5)" ::: "memory");
      else          asm volatile("s_waitcnt vmcnt(4)" ::: "memory");
    } else {
      asm volatile("s_waitcnt vmcnt(0)" ::: "memory");
    }
    asm volatile("s_barrier" ::: "memory");

    const char* base = lds + (kt & 1) * PERBUF;
    // this wave's K32 half: demand chunk q = kg*4+fq; slot = q ^ (row&7)
    const int coff = ((kg * 4 + fq) ^ (fr & 7)) * 16;
    short8 af[4], bfr[4];
#pragma unroll
    for (int im = 0; im < 4; ++im) {
      int row = 16 + wm + im * 16 + fr;               // row&7 == fr&7
      af[im] = *(const short8*)(base + row * 128 + coff);
    }
#pragma unroll
    for (int in = 0; in < 4; ++in) {
      int row = wn + in * 16 + fr;
      bfr[in] = *(const short8*)(base + ABYTES + row * 128 + coff);
    }
#pragma unroll
    for (int im = 0; im < 4; ++im)
#pragma unroll
      for (int in = 0; in < 4; ++in)
        acc[im][in] = __builtin_amdgcn_mfma_f32_16x16x32_bf16(
            af[im], bfr[in], acc[im][in], 0, 0, 0);
    if (wm == 0) {                      // warmup rows: static bfr indices
      short8 aw = *(const short8*)(base + fr * 128 + coff);
      accw[0] = __builtin_amdgcn_mfma_f32_16x16x32_bf16(aw, bfr[0], accw[0], 0, 0, 0);
      accw[1] = __builtin_amdgcn_mfma_f32_16x16x32_bf16(aw, bfr[1], accw[1], 0, 0, 0);
      accw[2] = __builtin_amdgcn_mfma_f32_16x16x32_bf16(aw, bfr[2], accw[2], 0, 0, 0);
      accw[3] = __builtin_amdgcn_mfma_f32_16x16x32_bf16(aw, bfr[3], accw[3], 0, 0, 0);
    }

    asm volatile("s_barrier" ::: "memory");   // buf consumed; safe to refill
  }

  // ---- cross-k reduction through LDS (one-time) ----
  __syncthreads();
  float* X = (float*)lds;               // acc: 16384 floats; accw: +2048
  if (kg == 1) {
#pragma unroll
    for (int im = 0; im < 4; ++im)
#pragma unroll
      for (int in = 0; in < 4; ++in)
        *(f32x4*)(X + wq * 4096 + (im * 4 + in) * 256 + lane * 4) = acc[im][in];
    if (wm == 0) {
#pragma unroll
      for (int iw = 0; iw < 4; ++iw)
        *(f32x4*)(X + 16384 + wq * 1024 + iw * 256 + lane * 4) = accw[iw];
    }
  }
  __syncthreads();
  if (kg == 0) {
#pragma unroll
    for (int im = 0; im < 4; ++im)
#pragma unroll
      for (int in = 0; in < 4; ++in)
        acc[im][in] += *(f32x4*)(X + wq * 4096 + (im * 4 + in) * 256 + lane * 4);
    if (wm == 0) {
#pragma unroll
      for (int iw = 0; iw < 4; ++iw)
        accw[iw] += *(f32x4*)(X + 16384 + wq * 1024 + iw * 256 + lane * 4);
    }
  }
  __syncthreads();

  // ---- S-tile (144 x 128, bf16, stride 132) into LDS ----
  uint16_t* Sl = (uint16_t*)lds;
  if (kg == 0) {
#pragma unroll
    for (int im = 0; im < 4; ++im)
#pragma unroll
      for (int in = 0; in < 4; ++in)
#pragma unroll
        for (int r = 0; r < 4; ++r)
          Sl[(16 + wm + im * 16 + fq * 4 + r) * SSTR + wn + in * 16 + fr] =
              f2bf(acc[im][in][r]);
    if (wm == 0) {
#pragma unroll
      for (int iw = 0; iw < 4; ++iw)
#pragma unroll
        for (int r = 0; r < 4; ++r)
          Sl[(fq * 4 + r) * SSTR + wn + iw * 16 + fr] = f2bf(accw[iw][r]);
    }
  }
  __syncthreads();

  // ---- scan: 4 threads per column, 32 t-steps each, 16-step warmup ----
  const int col   = tid & 127;
  const int chunk = tid >> 7;           // 0..3
  const float av  = a[n0 + col];
  float h = 0.f;
  if (!(m0 == 0 && chunk == 0)) {
#pragma unroll
    for (int i = 0; i < 16; ++i)
      h = av * h + bf2f(Sl[(chunk * 32 + i) * SSTR + col]);
  }
  float* op = out + (size_t)(m0 + chunk * 32) * HDIM + n0 + col;
#pragma unroll
  for (int i = 0; i < 32; ++i) {
    h = av * h + bf2f(Sl[(chunk * 32 + 16 + i) * SSTR + col]);
    op[(size_t)i * HDIM] = h;
  }
}

extern "C" void kernel_launch(void* const* d_in, const int* in_sizes, int n_in,
                              void* d_out, int out_size, void* d_ws, size_t ws_size,
                              hipStream_t stream) {
  const float* x = (const float*)d_in[0];   // (T, H)
  const float* a = (const float*)d_in[1];   // (H,)
  const float* B = (const float*)d_in[2];   // (H, H)
  float* out = (float*)d_out;               // (1, T, H) fp32

  uint16_t* xb  = (uint16_t*)d_ws;                                        // 16 MB
  uint16_t* Btb = (uint16_t*)((char*)d_ws + (size_t)16 * 1024 * 1024);    //  8 MB

  // x -> bf16  and  B -> Bt bf16 (fused)
  prep<<<4096 + 1024, 256, 0, stream>>>(x, B, xb, Btb);
  // fused GEMM + recurrence: 512 blocks x 512 threads, split-K in block
  gemm_scan<<<dim3(HDIM / BN, TDIM / BM), 512, 0, stream>>>(xb, Btb, a, out);
}